// Round 4
// baseline (193.691 us; speedup 1.0000x reference)
//
#include <hip/hip_runtime.h>
#include <math.h>

#define GDIM 152
#define NA 3
#define GG (GDIM * GDIM)   // 23104
#define EXP_CLAMP 1000.0f
#define NTHREADS 64        // single-wave blocks
#define TILE 256           // cells per block-iteration = 4 * NTHREADS
#define GSTRIDE (TILE + 1) // 257 float4s between group planes (bank offset 4/group)
#define TILES_TOTAL 8664   // 32*3*23104 / 256, exact
#define NTPB 3             // tiles per block (software pipeline depth)
#define NBLK (TILES_TOTAL / NTPB)  // 2888, exact

typedef float floatx4 __attribute__((ext_vector_type(4)));

__device__ __forceinline__ float sigmoidf(float v) {
    return 1.0f / (1.0f + __expf(-v));
}

// XOR swizzle on float4 entry index (bijective on [0,256)).
__device__ __forceinline__ int swz(int e) { return e ^ ((e >> 3) & 7); }

// Input base pointer for this thread's 4 cells of a tile (address-only; cheap,
// so pipeline prologue can issue loads without building the full context).
__device__ __forceinline__ const floatx4* make_ip(int tile, int t,
                                                  const float* __restrict__ x) {
    const int cbase = tile * TILE + 4 * t;
    const unsigned t2 = (unsigned)cbase / (unsigned)GG;   // b*NA + a
    const int pos = cbase - (int)t2 * GG;
    return (const floatx4*)x + (size_t)(t2 * 12u) * (GG / 4) + (pos >> 2);
}

struct TileCtx {
    floatx4* op;
    float gx0f, gyf, ah, aw, al;
};

// Full per-tile context. Anchor values come from a pre-loaded uniform table
// (selected per-thread) so no global load sits on the compute critical path.
__device__ __forceinline__ TileCtx make_ctx(int tile, int t, float* __restrict__ out,
        const float* atab /*9 floats: {h,w,l} x 3 anchors*/) {
    TileCtx c;
    const int tilebase = tile * TILE;
    const int cbase = tilebase + 4 * t;
    const unsigned t2 = (unsigned)cbase / (unsigned)GG;
    const int pos = cbase - (int)t2 * GG;
    const int gy = pos / GDIM;
    const int gx0 = pos - gy * GDIM;
    const int a = (int)(t2 % 3u);
    c.gx0f = (float)gx0;
    c.gyf  = (float)gy;
    c.op   = (floatx4*)out + (size_t)tilebase * 3;
    // per-thread select from uniform table (2 cndmask per value)
    c.ah = (a == 0) ? atab[0] : (a == 1) ? atab[3] : atab[6];
    c.aw = (a == 0) ? atab[1] : (a == 1) ? atab[4] : atab[7];
    c.al = (a == 0) ? atab[2] : (a == 1) ? atab[5] : atab[8];
    return c;
}

__device__ __forceinline__ void load12(const floatx4* __restrict__ ip, floatx4 r[12]) {
    const int PS = GG / 4;
#pragma unroll
    for (int k = 0; k < 12; ++k) r[k] = ip[k * PS];  // 12 independent dwordx4
}

// Phase 1: transcendental decode + LDS transpose-stage.
// Barrier at entry protects the previous tile's phase-2 LDS reads.
__device__ __forceinline__ void phase1(const TileCtx& c, const floatx4 r[12],
                                       floatx4* sh, int t, float stride) {
    __syncthreads();
#pragma unroll
    for (int J = 0; J < 4; ++J) {
        floatx4 o0, o1, o2;
        o0.x = (sigmoidf(r[0][J]) + c.gx0f + (float)J) * stride;
        o0.y = (sigmoidf(r[1][J]) + c.gyf) * stride;
        o0.z = sigmoidf(r[2][J]);
        o0.w = fminf(__expf(r[3][J]), EXP_CLAMP) * c.ah;
        o1.x = fminf(__expf(r[4][J]), EXP_CLAMP) * c.aw;
        o1.y = fminf(__expf(r[5][J]), EXP_CLAMP) * c.al;
        o1.z = r[6][J];
        o1.w = r[7][J];
        o2.x = sigmoidf(r[8][J]);
        o2.y = sigmoidf(r[9][J]);
        o2.z = sigmoidf(r[10][J]);
        o2.w = sigmoidf(r[11][J]);
        const int e = swz(4 * t + J);
        sh[0 * GSTRIDE + e] = o0;
        sh[1 * GSTRIDE + e] = o1;
        sh[2 * GSTRIDE + e] = o2;
    }
}

// Phase 2: lane-contiguous nontemporal stores of the 768-float4 tile.
__device__ __forceinline__ void phase2(const TileCtx& c, const floatx4* sh, int t) {
    __syncthreads();
#pragma unroll
    for (int k = 0; k < 12; ++k) {
        const int F = t + NTHREADS * k;
        const unsigned cell = (unsigned)F / 3u;
        const int g = F - (int)cell * 3;
        floatx4 v = sh[g * GSTRIDE + swz((int)cell)];
        __builtin_nontemporal_store(v, c.op + F);
    }
}

__global__ __launch_bounds__(NTHREADS) void yolo_decode_pipe(
    const float* __restrict__ x,
    const float* __restrict__ anchors,
    const int* __restrict__ img_size_p,
    float* __restrict__ out)
{
    __shared__ floatx4 sh[3 * GSTRIDE];   // 12,336 B -> ~12 blocks/CU (LDS cap)

    const int t = threadIdx.x;
    const float stride = (float)(*img_size_p) / (float)GDIM;  // 4.0
    const float inv_s = 1.0f / stride;

    // Uniform anchor table: {h,w,l} * inv_s * stride per anchor (compiler keeps
    // these in SGPRs; the *inv_s*stride matches the reference rounding exactly).
    float atab[9];
#pragma unroll
    for (int a = 0; a < 3; ++a) {
#pragma unroll
        for (int j = 0; j < 3; ++j)
            atab[a * 3 + j] = anchors[a * 5 + j] * inv_s * stride;
    }

    // Three tiles per block, strided so the global access footprint stays
    // spread across the grid exactly like the flat launch.
    const int tA = blockIdx.x;
    const int tB = tA + NBLK;
    const int tC = tA + 2 * NBLK;

    const floatx4* ipA = make_ip(tA, t, x);
    const floatx4* ipB = make_ip(tB, t, x);
    const floatx4* ipC = make_ip(tC, t, x);

    floatx4 ra[12], rb[12];
    load12(ipA, ra);          // 12 in flight
    load12(ipB, rb);          // 24 in flight

    {   // tile A
        TileCtx c = make_ctx(tA, t, out, atab);
        phase1(c, ra, sh, t, stride);   // waits only on ra (vmcnt(12))
        load12(ipC, ra);                // re-arm: tile C loads hide under A's
        phase2(c, sh, t);               // stores + B/C loads all in flight
    }
    {   // tile B
        TileCtx c = make_ctx(tB, t, out, atab);
        phase1(c, rb, sh, t, stride);
        phase2(c, sh, t);
    }
    {   // tile C
        TileCtx c = make_ctx(tC, t, out, atab);
        phase1(c, ra, sh, t, stride);
        phase2(c, sh, t);
    }
}

extern "C" void kernel_launch(void* const* d_in, const int* in_sizes, int n_in,
                              void* d_out, int out_size, void* d_ws, size_t ws_size,
                              hipStream_t stream) {
    const float* x        = (const float*)d_in[0];
    const float* anchors  = (const float*)d_in[1];
    const int*   img_size = (const int*)d_in[2];
    float*       out      = (float*)d_out;

    yolo_decode_pipe<<<NBLK, NTHREADS, 0, stream>>>(x, anchors, img_size, out);
}